// Round 9
// baseline (364.471 us; speedup 1.0000x reference)
//
#include <hip/hip_runtime.h>
#include <hip/hip_bf16.h>

// SDPA with materialized attention — single fused kernel, e resident in LDS.
// B=16, LQ=LK=2048, D=64. d_out = out [B,LQ,D] f32 then attn [B,LQ,LK] f32.
// Block = 16 consecutive q-rows x full k-range. 256 threads, ~75KB LDS, 2 blocks/CU.
namespace {
constexpr int kB = 16;
constexpr int kLQ = 2048;
constexpr int kLK = 2048;
constexpr int kD = 64;
constexpr float kLog2e = 1.44269504088896340736f;
constexpr int kEStr = 2056;   // e row stride in bf16 elems (2048 + 8 pad -> 2-way banks)
constexpr int kKStrB = 144;   // K-tile LDS row: 64 bf16 = 128B + 16B pad (16B-aligned)
constexpr int kMStrB = 72;    // mask-tile LDS row: 64B + 8 pad (18 dw -> distinct banks)
}

using short8 = __attribute__((ext_vector_type(8))) short;
using f32x4  = __attribute__((ext_vector_type(4))) float;

union S8U { short8 v; unsigned u[4]; unsigned long long q[2]; };

static __device__ __forceinline__ unsigned pk2(float lo, float hi) {
    __hip_bfloat162 h = __float22bfloat162_rn(float2{lo, hi});
    unsigned short a = __builtin_bit_cast(unsigned short, h.x);
    unsigned short b = __builtin_bit_cast(unsigned short, h.y);
    return (unsigned)a | ((unsigned)b << 16);
}
static __device__ __forceinline__ float bf2f(unsigned short s) {
    unsigned u = ((unsigned)s) << 16;
    return __builtin_bit_cast(float, u);
}

__global__ __launch_bounds__(256, 2) void sdpa_fused(
    const float* __restrict__ qg, const float* __restrict__ kg,
    const float* __restrict__ vg, const void* __restrict__ maskg,
    float* __restrict__ outg, float* __restrict__ attng)
{
    __shared__ unsigned short s_e[16][kEStr];                   // e bf16, 64.25 KB
    __shared__ __align__(16) unsigned char s_kst[64 * kKStrB];  // K sub-tile bf16 [64][64]
    __shared__ __align__(16) unsigned char s_mst[16 * kMStrB];  // mask flags [16][64]
    __shared__ float s_wsum[4][16];
    __shared__ float s_rinv[16];
    __shared__ int s_flag;

    const int tid = threadIdx.x;
    const int wave = tid >> 6;
    const int lane = tid & 63;
    const int r16 = lane & 15;
    const int g = lane >> 4;

    const int blk = blockIdx.x;
    const int b = blk >> 7;
    const int qt = blk & 127;
    const size_t grow0 = (size_t)b * kLQ + qt * 16;   // first global q-row

    // ---- mask dtype detection: int32 0/1 words have bytes 1..3 == 0 ----
    if (tid < 64) {
        unsigned w = ((const unsigned*)maskg)[tid];
        unsigned long long bal = __ballot((w & 0xFFFFFF00u) != 0u);
        if (tid == 0) s_flag = (bal != 0ull) ? 1 : 0;
    }
    __syncthreads();
    const bool mask_byte = (s_flag != 0);
    const unsigned char* mask_u8 = (const unsigned char*)maskg;
    const int* mask_i32 = (const int*)maskg;

    // ---- Q fragment (same 16 rows for all waves), scale folded (0.125*log2e) ----
    short8 q0, q1;
    {
        const float4* qp = (const float4*)(qg + (grow0 + r16) * kD);
        const float s = 0.125f * kLog2e;
        float4 x0 = qp[2*g + 0], x1 = qp[2*g + 1];
        float4 x2 = qp[2*g + 8], x3 = qp[2*g + 9];
        x0 *= s; x1 *= s; x2 *= s; x3 *= s;
        S8U a, c;
        a.u[0] = pk2(x0.x, x0.y); a.u[1] = pk2(x0.z, x0.w);
        a.u[2] = pk2(x1.x, x1.y); a.u[3] = pk2(x1.z, x1.w);
        c.u[0] = pk2(x2.x, x2.y); c.u[1] = pk2(x2.z, x2.w);
        c.u[2] = pk2(x3.x, x3.y); c.u[3] = pk2(x3.z, x3.w);
        q0 = a.v; q1 = c.v;
    }

    // stage-load index helpers (coalesced):
    const int srow = tid >> 4;           // 0..15
    const int sseg = tid & 15;           // 0..15
    const size_t kgbase = (size_t)b * kLK * kD;

    // ---- prefetch sub 0: K (4 rows-groups x float4) + mask word ----
    float4 kpre0, kpre1, kpre2, kpre3;
    unsigned mpre;
    {
        const float* kp = kg + kgbase + (size_t)srow * kD + sseg * 4;
        kpre0 = *(const float4*)(kp + 0  * kD);
        kpre1 = *(const float4*)(kp + 16 * kD);
        kpre2 = *(const float4*)(kp + 32 * kD);
        kpre3 = *(const float4*)(kp + 48 * kD);
        if (mask_byte) {
            mpre = *(const unsigned*)(mask_u8 + (grow0 + srow) * kLK + sseg * 4);
        } else {
            const int4 m = *(const int4*)(mask_i32 + (grow0 + srow) * kLK + sseg * 4);
            mpre = (m.x ? 1u : 0u) | (m.y ? 0x100u : 0u) | (m.z ? 0x10000u : 0u) | (m.w ? 0x1000000u : 0u);
        }
    }

    float wsum = 0.f;

    for (int sub = 0; sub < kLK / 64; ++sub) {
        // ---- write staged regs -> LDS ----
        {
            uint2 p0{ pk2(kpre0.x, kpre0.y), pk2(kpre0.z, kpre0.w) };
            uint2 p1{ pk2(kpre1.x, kpre1.y), pk2(kpre1.z, kpre1.w) };
            uint2 p2{ pk2(kpre2.x, kpre2.y), pk2(kpre2.z, kpre2.w) };
            uint2 p3{ pk2(kpre3.x, kpre3.y), pk2(kpre3.z, kpre3.w) };
            *(uint2*)(s_kst + (srow +  0) * kKStrB + sseg * 8) = p0;
            *(uint2*)(s_kst + (srow + 16) * kKStrB + sseg * 8) = p1;
            *(uint2*)(s_kst + (srow + 32) * kKStrB + sseg * 8) = p2;
            *(uint2*)(s_kst + (srow + 48) * kKStrB + sseg * 8) = p3;
            *(unsigned*)(s_mst + srow * kMStrB + sseg * 4) = mpre;
        }
        __syncthreads();   // A: K/mask tile visible

        // ---- issue next sub's loads (hidden under compute) ----
        if (sub + 1 < kLK / 64) {
            const int csub = (sub + 1) * 64;
            const float* kp = kg + kgbase + (size_t)(csub + srow) * kD + sseg * 4;
            kpre0 = *(const float4*)(kp + 0  * kD);
            kpre1 = *(const float4*)(kp + 16 * kD);
            kpre2 = *(const float4*)(kp + 32 * kD);
            kpre3 = *(const float4*)(kp + 48 * kD);
            if (mask_byte) {
                mpre = *(const unsigned*)(mask_u8 + (grow0 + srow) * kLK + csub + sseg * 4);
            } else {
                const int4 m = *(const int4*)(mask_i32 + (grow0 + srow) * kLK + csub + sseg * 4);
                mpre = (m.x ? 1u : 0u) | (m.y ? 0x100u : 0u) | (m.z ? 0x10000u : 0u) | (m.w ? 0x1000000u : 0u);
            }
        }

        // ---- compute: wave w owns cols [sub*64 + w*16, +16) ----
        const unsigned char* kb = s_kst + (wave * 16 + r16) * kKStrB;
        const short8 kA0 = *(const short8*)(kb + g * 16);
        const short8 kA1 = *(const short8*)(kb + 64 + g * 16);
        f32x4 acc = {0.f, 0.f, 0.f, 0.f};
        acc = __builtin_amdgcn_mfma_f32_16x16x32_bf16(kA0, q0, acc, 0, 0, 0);
        acc = __builtin_amdgcn_mfma_f32_16x16x32_bf16(kA1, q1, acc, 0, 0, 0);

        // lane reg r: S[q=r16][col = sub*64 + wave*16 + 4g + r]
        const unsigned mw = *(const unsigned*)(s_mst + r16 * kMStrB + wave * 16 + 4 * g);
        float e4[4];
#pragma unroll
        for (int r = 0; r < 4; ++r)
            e4[r] = ((mw >> (8*r)) & 0xFFu) ? 0.f : __builtin_amdgcn_exp2f(acc[r]);
        wsum += (e4[0] + e4[1]) + (e4[2] + e4[3]);
        const unsigned long long pe = (unsigned long long)pk2(e4[0], e4[1])
                                    | ((unsigned long long)pk2(e4[2], e4[3]) << 32);
        *(unsigned long long*)&s_e[r16][sub * 64 + wave * 16 + 4 * g] = pe;
        __syncthreads();   // B: tile reads done before next stage-write
    }

    // ---- rowsums -> rinv ----
    wsum += __shfl_xor(wsum, 16, 64);
    wsum += __shfl_xor(wsum, 32, 64);
    if (g == 0) s_wsum[wave][r16] = wsum;
    __syncthreads();
    if (tid < 16) {
        const float rs = s_wsum[0][tid] + s_wsum[1][tid] + s_wsum[2][tid] + s_wsum[3][tid];
        s_rinv[tid] = __builtin_amdgcn_rcpf(rs);
    }
    __syncthreads();

    // ---- attn rows: 16 x 8KB sequential stores straight from LDS ----
#pragma unroll 2
    for (int r = 0; r < 16; ++r) {
        const float rinv = s_rinv[r];
        const short8 ev = *(const short8*)&s_e[r][tid * 8];
        f32x4 a0, a1;
        a0[0] = bf2f((unsigned short)ev[0]) * rinv;
        a0[1] = bf2f((unsigned short)ev[1]) * rinv;
        a0[2] = bf2f((unsigned short)ev[2]) * rinv;
        a0[3] = bf2f((unsigned short)ev[3]) * rinv;
        a1[0] = bf2f((unsigned short)ev[4]) * rinv;
        a1[1] = bf2f((unsigned short)ev[5]) * rinv;
        a1[2] = bf2f((unsigned short)ev[6]) * rinv;
        a1[3] = bf2f((unsigned short)ev[7]) * rinv;
        float* ap = attng + (grow0 + r) * (size_t)kLK + tid * 8;
        *(f32x4*)ap = a0;
        *(f32x4*)(ap + 4) = a1;
    }

    // ---- PV from LDS e: wave w owns d-cols [16w, 16w+16), 1-deep V prefetch ----
    {
        const int d0 = wave * 16;
        const float* vbase = vg + (size_t)b * kLK * kD + d0 + r16;
        float vp0, vp1, vp2, vp3, vp4, vp5, vp6, vp7;
        {
            const float* vp = vbase + (size_t)(8 * g) * kD;
            vp0 = vp[0*kD]; vp1 = vp[1*kD]; vp2 = vp[2*kD]; vp3 = vp[3*kD];
            vp4 = vp[4*kD]; vp5 = vp[5*kD]; vp6 = vp[6*kD]; vp7 = vp[7*kD];
        }
        f32x4 acc = {0.f, 0.f, 0.f, 0.f};
        for (int kt = 0; kt < kLK / 32; ++kt) {
            const int kk0 = kt * 32 + 8 * g;
            const float c0 = vp0, c1 = vp1, c2 = vp2, c3 = vp3;
            const float c4 = vp4, c5 = vp5, c6 = vp6, c7 = vp7;
            if (kt + 1 < kLK / 32) {
                const float* vp = vbase + (size_t)(kk0 + 32) * kD;
                vp0 = vp[0*kD]; vp1 = vp[1*kD]; vp2 = vp[2*kD]; vp3 = vp[3*kD];
                vp4 = vp[4*kD]; vp5 = vp[5*kD]; vp6 = vp[6*kD]; vp7 = vp[7*kD];
            }
            const short8 af = *(const short8*)&s_e[r16][kk0];
            S8U bv;
            bv.u[0] = pk2(c0, c1); bv.u[1] = pk2(c2, c3);
            bv.u[2] = pk2(c4, c5); bv.u[3] = pk2(c6, c7);
            acc = __builtin_amdgcn_mfma_f32_16x16x32_bf16(af, bv.v, acc, 0, 0, 0);
        }
#pragma unroll
        for (int r = 0; r < 4; ++r) {
            const int m = 4 * g + r;
            outg[(grow0 + m) * kD + d0 + r16] = acc[r] * s_rinv[m];
        }
    }
}

extern "C" void kernel_launch(void* const* d_in, const int* in_sizes, int n_in,
                              void* d_out, int out_size, void* d_ws, size_t ws_size,
                              hipStream_t stream) {
    (void)in_sizes; (void)n_in; (void)out_size; (void)d_ws; (void)ws_size;
    const float* q = (const float*)d_in[0];
    const float* k = (const float*)d_in[1];
    const float* v = (const float*)d_in[2];
    const void* mask = d_in[3];
    float* out = (float*)d_out;
    float* attn = out + (size_t)kB * kLQ * kD;
    sdpa_fused<<<dim3(kB * 128), 256, 0, stream>>>(q, k, v, mask, out, attn);
}